// Round 7
// baseline (153.976 us; speedup 1.0000x reference)
//
#include <hip/hip_runtime.h>
#include <hip/hip_bf16.h>
#include <stdint.h>

#define N_ROWS 16384
#define D_DIM  512
#define C_DIM  1024

typedef __attribute__((ext_vector_type(4))) float f32x4;
typedef __attribute__((ext_vector_type(8))) short bf16x8;

// f32 -> bf16 bits, round-to-nearest-even
__device__ __forceinline__ short bfbits(float x) {
  uint32_t u = __float_as_uint(x);
  uint32_t r = (u + 0x7fffu + ((u >> 16) & 1u)) >> 16;
  return (short)r;
}

__device__ __forceinline__ void gload16(const short* g, const short* l) {
  __builtin_amdgcn_global_load_lds(
      (const __attribute__((address_space(1))) void*)g,
      (__attribute__((address_space(3))) void*)l, 16, 0, 0);
}

// ---- fused prep: inputs->bf16+|x|^2, centers->bf16+|c|^2, W -> W^T bf16 ----
__global__ __launch_bounds__(256) void fused_prep(
    const float* __restrict__ inputs, const float* __restrict__ centers,
    const float* __restrict__ W, short* __restrict__ inb,
    short* __restrict__ cenb, short* __restrict__ wT,
    float* __restrict__ x2, float* __restrict__ c2) {
  int bid = blockIdx.x;
  if (bid < 4096 + 256) {
    // row prep: 4 waves/block, one wave per row of 512 floats
    const float* src; short* dst; float* sq; int row;
    if (bid < 4096) { src = inputs; dst = inb; sq = x2; row = bid * 4 + (threadIdx.x >> 6); }
    else { src = centers; dst = cenb; sq = c2; row = (bid - 4096) * 4 + (threadIdx.x >> 6); }
    int lane = threadIdx.x & 63;
    const float4* s = reinterpret_cast<const float4*>(src + (size_t)row * D_DIM) + lane * 2;
    float4 v0 = s[0], v1 = s[1];
    float ss = v0.x*v0.x + v0.y*v0.y + v0.z*v0.z + v0.w*v0.w
             + v1.x*v1.x + v1.y*v1.y + v1.z*v1.z + v1.w*v1.w;
    bf16x8 o;
    o[0]=bfbits(v0.x); o[1]=bfbits(v0.y); o[2]=bfbits(v0.z); o[3]=bfbits(v0.w);
    o[4]=bfbits(v1.x); o[5]=bfbits(v1.y); o[6]=bfbits(v1.z); o[7]=bfbits(v1.w);
    *reinterpret_cast<bf16x8*>(dst + (size_t)row * D_DIM + lane * 8) = o;
    #pragma unroll
    for (int off = 32; off; off >>= 1) ss += __shfl_down(ss, off, 64);
    if (lane == 0) sq[row] = ss;
  } else {
    // transpose W[c][j] -> wT[j][c] (bf16)
    __shared__ float tile[32][33];
    int b2 = bid - 4352;
    int j0 = (b2 & 31) * 32;
    int c0 = (b2 >> 5) * 32;
    int tx = threadIdx.x & 31;
    int ty = threadIdx.x >> 5;  // 0..7
    #pragma unroll
    for (int i = 0; i < 32; i += 8)
      tile[ty + i][tx] = W[(size_t)(c0 + ty + i) * C_DIM + j0 + tx];
    __syncthreads();
    #pragma unroll
    for (int i = 0; i < 32; i += 8)
      wT[(size_t)(j0 + ty + i) * C_DIM + c0 + tx] = bfbits(tile[tx][ty + i]);
  }
}

// ---- 256x256 4-phase BT GEMM: C[M][1024] = A[M][K] x B[1024][K]^T (bf16 in) ----
// 8 waves (2Mx4N), BK=64, dbuf LDS 128KB, st-swizzle c^((r&7)<<3).
// One counted vmcnt(6) per K-tile (T4): P4 issues 6 loads for tile t+2 into
// just-freed current-buffer regions; P1 issues remaining 2 for tile t+1.
// EPI 0: RBF densities epilogue -> bf16    EPI 1: plain f32 store
template<int EPI>
__global__ __launch_bounds__(512, 2)
void gemm256(const short* __restrict__ A, const short* __restrict__ B,
             void* __restrict__ Cp, const float* __restrict__ x2,
             const float* __restrict__ c2, const float* __restrict__ gptr,
             int K) {
  __shared__ __align__(16) short lds[65536];  // A: [0,32768)  B: [32768,65536)
  short* As = lds;
  short* Bs = lds + 32768;

  const int tid  = threadIdx.x;
  const int lane = tid & 63;
  const int wid  = tid >> 6;
  const int wr = wid >> 2;   // 0..1
  const int wc = wid & 3;    // 0..3

  // XCD-aware bijective swizzle: 64 row-blocks x 4 col-blocks, 256 blocks.
  const int bid  = blockIdx.x;
  const int brow = (bid & 7) * 8 + (bid >> 5);
  const int bcol = (bid >> 3) & 3;
  const int row0 = brow * 256, col0 = bcol * 256;

  const int NT = K >> 6;

  // fragment ds_read addressing (swizzled): elem (r,c) stored at c^((r&7)<<3)
  const int l15 = lane & 15;
  const int lk  = (lane >> 4) * 8;
  const int sw  = (lane & 7) << 3;
  const int swHi = sw & 32, swLo = sw & 24;
  const int ca0 = swHi | (lk ^ swLo);          // kk=0 swizzled col (shorts)
  const int ca1 = (swHi ^ 32) | (lk ^ swLo);   // kk=1
  const int aRow = (wr * 128 + l15) * 64;
  const int bRow = (wc * 64  + l15) * 64;

  // staging addressing: unit = 64 rows x 64 shorts = 8KB = 512 threads x 16B
  const int rowL = tid >> 3;                        // 0..63
  const int chS  = ((tid & 7) ^ (rowL & 7)) << 3;   // pre-swizzled source chunk
  const short* gA = A + (size_t)(row0 + rowL) * K + chS;
  const short* gB = B + (size_t)(col0 + rowL) * K + chS;
  const int ldsT = tid * 8;

#define STG_A(buf, u, kt) gload16(gA + (size_t)((u) * 64) * K + (kt), As + (buf) * 16384 + (u) * 4096 + ldsT)
#define STG_B(buf, u, kt) gload16(gB + (size_t)((u) * 64) * K + (kt), Bs + (buf) * 16384 + (u) * 4096 + ldsT)

  f32x4 acc[8][4] = {};

  // prologue: tile0 (8 loads) -> buf0; tile1 partial (A u0,u2 + B u0-3) -> buf1
  STG_A(0, 0, 0); STG_A(0, 2, 0); STG_A(0, 1, 0); STG_A(0, 3, 0);
  STG_B(0, 0, 0); STG_B(0, 1, 0); STG_B(0, 2, 0); STG_B(0, 3, 0);
  {
    const int kt1 = ((NT > 1) ? 1 : 0) << 6;
    STG_A(1, 0, kt1); STG_A(1, 2, kt1);
    STG_B(1, 0, kt1); STG_B(1, 1, kt1); STG_B(1, 2, kt1); STG_B(1, 3, kt1);
  }
  asm volatile("s_waitcnt vmcnt(6)" ::: "memory");  // tile0 fully resident
  __builtin_amdgcn_s_barrier();

  bf16x8 a[4], b0[4], b1[4];
  for (int t = 0; t < NT; ++t) {
    const int bsel = t & 1, nb = bsel ^ 1;
    const short* aB = As + bsel * 16384;
    const short* bB = Bs + bsel * 16384;
    const int kt1 = ((t + 1 < NT) ? (t + 1) : (NT - 1)) << 6;
    const int kt2 = ((t + 2 < NT) ? (t + 2) : (NT - 1)) << 6;

    // ---- P1: a(m0-3,kk0) + b(kk0); STG(t+1 -> nb): A u1,u3 ----
    // (nb's A u1,u3 freed by end-P4(t-1) barrier)
    #pragma unroll
    for (int i = 0; i < 4; ++i) a[i]  = *(const bf16x8*)(aB + aRow + i * 1024 + ca0);
    #pragma unroll
    for (int n = 0; n < 4; ++n) b0[n] = *(const bf16x8*)(bB + bRow + n * 1024 + ca0);
    STG_A(nb, 1, kt1); STG_A(nb, 3, kt1);
    __builtin_amdgcn_s_barrier();
    asm volatile("s_waitcnt lgkmcnt(0)" ::: "memory");
    __builtin_amdgcn_sched_barrier(0);
    __builtin_amdgcn_s_setprio(1);
    #pragma unroll
    for (int i = 0; i < 4; ++i)
      #pragma unroll
      for (int n = 0; n < 4; ++n)
        acc[i][n] = __builtin_amdgcn_mfma_f32_16x16x32_bf16(a[i], b0[n], acc[i][n], 0, 0, 0);
    __builtin_amdgcn_s_setprio(0);
    __builtin_amdgcn_s_barrier();

    // ---- P2: a(m4-7,kk0) ----
    #pragma unroll
    for (int i = 0; i < 4; ++i) a[i] = *(const bf16x8*)(aB + aRow + (4 + i) * 1024 + ca0);
    __builtin_amdgcn_s_barrier();
    asm volatile("s_waitcnt lgkmcnt(0)" ::: "memory");
    __builtin_amdgcn_sched_barrier(0);
    __builtin_amdgcn_s_setprio(1);
    #pragma unroll
    for (int i = 0; i < 4; ++i)
      #pragma unroll
      for (int n = 0; n < 4; ++n)
        acc[4 + i][n] = __builtin_amdgcn_mfma_f32_16x16x32_bf16(a[i], b0[n], acc[4 + i][n], 0, 0, 0);
    __builtin_amdgcn_s_setprio(0);
    __builtin_amdgcn_s_barrier();

    // ---- P3: a(m0-3,kk1) + b(kk1) ----
    #pragma unroll
    for (int i = 0; i < 4; ++i) a[i]  = *(const bf16x8*)(aB + aRow + i * 1024 + ca1);
    #pragma unroll
    for (int n = 0; n < 4; ++n) b1[n] = *(const bf16x8*)(bB + bRow + n * 1024 + ca1);
    __builtin_amdgcn_s_barrier();
    asm volatile("s_waitcnt lgkmcnt(0)" ::: "memory");
    __builtin_amdgcn_sched_barrier(0);
    __builtin_amdgcn_s_setprio(1);
    #pragma unroll
    for (int i = 0; i < 4; ++i)
      #pragma unroll
      for (int n = 0; n < 4; ++n)
        acc[i][n] = __builtin_amdgcn_mfma_f32_16x16x32_bf16(a[i], b1[n], acc[i][n], 0, 0, 0);
    __builtin_amdgcn_s_setprio(0);
    __builtin_amdgcn_s_barrier();

    // ---- P4: a(m4-7,kk1); STG(t+2 -> cur buf): A u0,u2 + B u0-3 ----
    // (cur's A u0,u2 and all B freed by end-P3 barrier; disjoint from P4's reads)
    #pragma unroll
    for (int i = 0; i < 4; ++i) a[i] = *(const bf16x8*)(aB + aRow + (4 + i) * 1024 + ca1);
    STG_A(bsel, 0, kt2); STG_A(bsel, 2, kt2);
    STG_B(bsel, 0, kt2); STG_B(bsel, 1, kt2); STG_B(bsel, 2, kt2); STG_B(bsel, 3, kt2);
    asm volatile("s_waitcnt vmcnt(6)" ::: "memory");  // tile t+1 fully resident
    __builtin_amdgcn_s_barrier();
    asm volatile("s_waitcnt lgkmcnt(0)" ::: "memory");
    __builtin_amdgcn_sched_barrier(0);
    __builtin_amdgcn_s_setprio(1);
    #pragma unroll
    for (int i = 0; i < 4; ++i)
      #pragma unroll
      for (int n = 0; n < 4; ++n)
        acc[4 + i][n] = __builtin_amdgcn_mfma_f32_16x16x32_bf16(a[i], b1[n], acc[4 + i][n], 0, 0, 0);
    __builtin_amdgcn_s_setprio(0);
    __builtin_amdgcn_s_barrier();
  }

  // epilogue. C/D layout: col = lane&15 (B side), row = (lane>>4)*4 + reg (A side)
  const int colB = col0 + wc * 64 + l15;
  const int rBase = row0 + wr * 128 + ((lane >> 4) << 2);

  if constexpr (EPI == 0) {
    short* Dm = (short*)Cp;
    const float g = *gptr;
    float cc2[4];
    #pragma unroll
    for (int n = 0; n < 4; ++n) cc2[n] = c2[colB + n * 16];
    #pragma unroll
    for (int m = 0; m < 8; ++m) {
      #pragma unroll
      for (int r = 0; r < 4; ++r) {
        const int row = rBase + m * 16 + r;
        const float xr = x2[row];
        size_t base = (size_t)row * C_DIM + colB;
        #pragma unroll
        for (int n = 0; n < 4; ++n) {
          float v = fmaxf(xr + cc2[n] - 2.0f * acc[m][n][r], 0.0f);
          Dm[base + n * 16] = bfbits(__expf(-g * v));
        }
      }
    }
  } else {
    float* Dm = (float*)Cp;
    #pragma unroll
    for (int m = 0; m < 8; ++m) {
      #pragma unroll
      for (int r = 0; r < 4; ++r) {
        const int row = rBase + m * 16 + r;
        size_t base = (size_t)row * C_DIM + colB;
        #pragma unroll
        for (int n = 0; n < 4; ++n)
          Dm[base + n * 16] = acc[m][n][r];
      }
    }
  }
#undef STG_A
#undef STG_B
}

extern "C" void kernel_launch(void* const* d_in, const int* in_sizes, int n_in,
                              void* d_out, int out_size, void* d_ws, size_t ws_size,
                              hipStream_t stream) {
  const float* inputs  = (const float*)d_in[0];
  const float* centers = (const float*)d_in[1];
  const float* gamma   = (const float*)d_in[2];
  const float* norm    = (const float*)d_in[3];
  float* out = (float*)d_out;

  char* ws = (char*)d_ws;
  short* inb  = (short*)(ws);                            // 16 MiB  bf16 inputs
  short* cenb = (short*)(ws + (16u << 20));              //  1 MiB  bf16 centers
  short* wT   = (short*)(ws + (17u << 20));              //  2 MiB  bf16 norm^T
  float* x2   = (float*)(ws + (19u << 20));              // 64 KiB  ||x||^2
  float* c2   = (float*)(ws + (19u << 20) + (1u << 16)); //  4 KiB  ||c||^2
  short* dens = (short*)(ws + (20u << 20));              // 32 MiB  bf16 densities

  fused_prep<<<5376, 256, 0, stream>>>(inputs, centers, norm, inb, cenb, wT, x2, c2);
  gemm256<0><<<256, 512, 0, stream>>>(inb, cenb, dens, x2, c2, gamma, D_DIM);
  gemm256<1><<<256, 512, 0, stream>>>(dens, wT, out, nullptr, nullptr, nullptr, C_DIM);
}

// Round 9
// 151.395 us; speedup vs baseline: 1.0170x; 1.0170x over previous
//
#include <hip/hip_runtime.h>
#include <hip/hip_bf16.h>
#include <stdint.h>

#define N_ROWS 16384
#define D_DIM  512
#define C_DIM  1024

typedef __attribute__((ext_vector_type(4))) float f32x4;
typedef __attribute__((ext_vector_type(8))) short bf16x8;

// f32 -> bf16 bits, round-to-nearest-even
__device__ __forceinline__ short bfbits(float x) {
  uint32_t u = __float_as_uint(x);
  uint32_t r = (u + 0x7fffu + ((u >> 16) & 1u)) >> 16;
  return (short)r;
}

__device__ __forceinline__ void gload16(const short* g, const short* l) {
  __builtin_amdgcn_global_load_lds(
      (const __attribute__((address_space(1))) void*)g,
      (__attribute__((address_space(3))) void*)l, 16, 0, 0);
}

// ---- fused prep: inputs->bf16+|x|^2, centers->bf16+|c|^2, W -> W^T bf16 ----
__global__ __launch_bounds__(256) void fused_prep(
    const float* __restrict__ inputs, const float* __restrict__ centers,
    const float* __restrict__ W, short* __restrict__ inb,
    short* __restrict__ cenb, short* __restrict__ wT,
    float* __restrict__ x2, float* __restrict__ c2) {
  int bid = blockIdx.x;
  if (bid < 4096 + 256) {
    // row prep: 4 waves/block, one wave per row of 512 floats
    const float* src; short* dst; float* sq; int row;
    if (bid < 4096) { src = inputs; dst = inb; sq = x2; row = bid * 4 + (threadIdx.x >> 6); }
    else { src = centers; dst = cenb; sq = c2; row = (bid - 4096) * 4 + (threadIdx.x >> 6); }
    int lane = threadIdx.x & 63;
    const float4* s = reinterpret_cast<const float4*>(src + (size_t)row * D_DIM) + lane * 2;
    float4 v0 = s[0], v1 = s[1];
    float ss = v0.x*v0.x + v0.y*v0.y + v0.z*v0.z + v0.w*v0.w
             + v1.x*v1.x + v1.y*v1.y + v1.z*v1.z + v1.w*v1.w;
    bf16x8 o;
    o[0]=bfbits(v0.x); o[1]=bfbits(v0.y); o[2]=bfbits(v0.z); o[3]=bfbits(v0.w);
    o[4]=bfbits(v1.x); o[5]=bfbits(v1.y); o[6]=bfbits(v1.z); o[7]=bfbits(v1.w);
    *reinterpret_cast<bf16x8*>(dst + (size_t)row * D_DIM + lane * 8) = o;
    #pragma unroll
    for (int off = 32; off; off >>= 1) ss += __shfl_down(ss, off, 64);
    if (lane == 0) sq[row] = ss;
  } else {
    // transpose W[c][j] -> wT[j][c] (bf16)
    __shared__ float tile[32][33];
    int b2 = bid - 4352;
    int j0 = (b2 & 31) * 32;
    int c0 = (b2 >> 5) * 32;
    int tx = threadIdx.x & 31;
    int ty = threadIdx.x >> 5;  // 0..7
    #pragma unroll
    for (int i = 0; i < 32; i += 8)
      tile[ty + i][tx] = W[(size_t)(c0 + ty + i) * C_DIM + j0 + tx];
    __syncthreads();
    #pragma unroll
    for (int i = 0; i < 32; i += 8)
      wT[(size_t)(j0 + ty + i) * C_DIM + c0 + tx] = bfbits(tile[tx][ty + i]);
  }
}

// ---- 256x256 BT GEMM, 1 barrier per K-tile, compiler-scheduled region ----
// C[M][1024] = A[M][K](bf16) x B[1024][K](bf16)^T
// 8 waves (2Mx4N), BK=64, dbuf LDS 128KB, st-swizzle c^((r&7)<<3).
// Whole tile t+1 staged in one batch into nb (all nb regions last read in
// tile t-1, free after previous end-of-tile barrier). One vmcnt(0)+s_barrier
// +sched_barrier(0) per tile; issue->wait distance ~= full tile >> HBM latency.
// Compiler schedules 64 MFMA || 24 ds_read || 8 gload with fine lgkm counts.
// EPI 0: RBF densities epilogue -> bf16    EPI 1: plain f32 store
template<int EPI>
__global__ __launch_bounds__(512, 2)
void gemm256(const short* __restrict__ A, const short* __restrict__ B,
             void* __restrict__ Cp, const float* __restrict__ x2,
             const float* __restrict__ c2, const float* __restrict__ gptr,
             int K) {
  __shared__ __align__(16) short lds[65536];  // A: [0,32768)  B: [32768,65536)
  short* As = lds;
  short* Bs = lds + 32768;

  const int tid  = threadIdx.x;
  const int lane = tid & 63;
  const int wid  = tid >> 6;
  const int wr = wid >> 2;   // 0..1
  const int wc = wid & 3;    // 0..3

  // XCD-aware bijective swizzle: 64 row-blocks x 4 col-blocks, 256 blocks.
  const int bid  = blockIdx.x;
  const int brow = (bid & 7) * 8 + (bid >> 5);
  const int bcol = (bid >> 3) & 3;
  const int row0 = brow * 256, col0 = bcol * 256;

  const int NT = K >> 6;

  // fragment ds_read addressing (swizzled): elem (r,c) stored at c^((r&7)<<3)
  const int l15 = lane & 15;
  const int lk  = (lane >> 4) * 8;
  const int sw  = (lane & 7) << 3;
  const int swHi = sw & 32, swLo = sw & 24;
  const int ca0 = swHi | (lk ^ swLo);          // kk=0 swizzled col (shorts)
  const int ca1 = (swHi ^ 32) | (lk ^ swLo);   // kk=1
  const int aRow = (wr * 128 + l15) * 64;
  const int bRow = (wc * 64  + l15) * 64;

  // staging addressing: unit = 64 rows x 64 shorts = 8KB = 512 threads x 16B
  const int rowL = tid >> 3;                        // 0..63
  const int chS  = ((tid & 7) ^ (rowL & 7)) << 3;   // pre-swizzled source chunk
  const short* gA = A + (size_t)(row0 + rowL) * K + chS;
  const short* gB = B + (size_t)(col0 + rowL) * K + chS;
  const int ldsT = tid * 8;

#define STG_A(buf, u, kt) gload16(gA + (size_t)((u) * 64) * K + (kt), As + (buf) * 16384 + (u) * 4096 + ldsT)
#define STG_B(buf, u, kt) gload16(gB + (size_t)((u) * 64) * K + (kt), Bs + (buf) * 16384 + (u) * 4096 + ldsT)
#define STG_TILE(buf, kt) do { \
    STG_A(buf, 0, kt); STG_A(buf, 1, kt); STG_A(buf, 2, kt); STG_A(buf, 3, kt); \
    STG_B(buf, 0, kt); STG_B(buf, 1, kt); STG_B(buf, 2, kt); STG_B(buf, 3, kt); \
  } while (0)

  f32x4 acc[8][4] = {};

  // prologue: tile0 -> buf0
  STG_TILE(0, 0);
  asm volatile("s_waitcnt vmcnt(0)" ::: "memory");
  __builtin_amdgcn_s_barrier();
  __builtin_amdgcn_sched_barrier(0);

  for (int t = 0; t < NT; ++t) {
    const int bsel = t & 1, nb = bsel ^ 1;
    const short* aB = As + bsel * 16384;
    const short* bB = Bs + bsel * 16384;

    // stage tile t+1 -> nb (regions last read in tile t-1; free since the
    // previous end-of-tile barrier)
    if (t + 1 < NT) {
      const int kt1 = (t + 1) << 6;
      STG_TILE(nb, kt1);
    }

    // whole-tile compute region: compiler schedules reads/MFMA freely
    bf16x8 a0[4], a1[4], b0[4], b1[4];
    #pragma unroll
    for (int i = 0; i < 4; ++i) a0[i] = *(const bf16x8*)(aB + aRow + i * 1024 + ca0);
    #pragma unroll
    for (int n = 0; n < 4; ++n) b0[n] = *(const bf16x8*)(bB + bRow + n * 1024 + ca0);
    #pragma unroll
    for (int i = 0; i < 4; ++i)
      #pragma unroll
      for (int n = 0; n < 4; ++n)
        acc[i][n] = __builtin_amdgcn_mfma_f32_16x16x32_bf16(a0[i], b0[n], acc[i][n], 0, 0, 0);
    #pragma unroll
    for (int i = 0; i < 4; ++i) a1[i] = *(const bf16x8*)(aB + aRow + (4 + i) * 1024 + ca0);
    #pragma unroll
    for (int i = 0; i < 4; ++i)
      #pragma unroll
      for (int n = 0; n < 4; ++n)
        acc[4 + i][n] = __builtin_amdgcn_mfma_f32_16x16x32_bf16(a1[i], b0[n], acc[4 + i][n], 0, 0, 0);
    #pragma unroll
    for (int i = 0; i < 4; ++i) a0[i] = *(const bf16x8*)(aB + aRow + i * 1024 + ca1);
    #pragma unroll
    for (int n = 0; n < 4; ++n) b1[n] = *(const bf16x8*)(bB + bRow + n * 1024 + ca1);
    #pragma unroll
    for (int i = 0; i < 4; ++i)
      #pragma unroll
      for (int n = 0; n < 4; ++n)
        acc[i][n] = __builtin_amdgcn_mfma_f32_16x16x32_bf16(a0[i], b1[n], acc[i][n], 0, 0, 0);
    #pragma unroll
    for (int i = 0; i < 4; ++i) a1[i] = *(const bf16x8*)(aB + aRow + (4 + i) * 1024 + ca1);
    #pragma unroll
    for (int i = 0; i < 4; ++i)
      #pragma unroll
      for (int n = 0; n < 4; ++n)
        acc[4 + i][n] = __builtin_amdgcn_mfma_f32_16x16x32_bf16(a1[i], b1[n], acc[4 + i][n], 0, 0, 0);

    // end of tile: wait staged tile t+1 (issued ~full tile ago), sync, pin
    asm volatile("s_waitcnt vmcnt(0)" ::: "memory");
    __builtin_amdgcn_s_barrier();
    __builtin_amdgcn_sched_barrier(0);
  }

  // epilogue. C/D layout: col = lane&15 (B side), row = (lane>>4)*4 + reg (A side)
  const int colB = col0 + wc * 64 + l15;
  const int rBase = row0 + wr * 128 + ((lane >> 4) << 2);

  if constexpr (EPI == 0) {
    short* Dm = (short*)Cp;
    const float g = *gptr;
    float cc2[4];
    #pragma unroll
    for (int n = 0; n < 4; ++n) cc2[n] = c2[colB + n * 16];
    #pragma unroll
    for (int m = 0; m < 8; ++m) {
      #pragma unroll
      for (int r = 0; r < 4; ++r) {
        const int row = rBase + m * 16 + r;
        const float xr = x2[row];
        size_t base = (size_t)row * C_DIM + colB;
        #pragma unroll
        for (int n = 0; n < 4; ++n) {
          float v = fmaxf(xr + cc2[n] - 2.0f * acc[m][n][r], 0.0f);
          Dm[base + n * 16] = bfbits(__expf(-g * v));
        }
      }
    }
  } else {
    float* Dm = (float*)Cp;
    #pragma unroll
    for (int m = 0; m < 8; ++m) {
      #pragma unroll
      for (int r = 0; r < 4; ++r) {
        const int row = rBase + m * 16 + r;
        size_t base = (size_t)row * C_DIM + colB;
        #pragma unroll
        for (int n = 0; n < 4; ++n)
          Dm[base + n * 16] = acc[m][n][r];
      }
    }
  }
#undef STG_A
#undef STG_B
#undef STG_TILE
}

extern "C" void kernel_launch(void* const* d_in, const int* in_sizes, int n_in,
                              void* d_out, int out_size, void* d_ws, size_t ws_size,
                              hipStream_t stream) {
  const float* inputs  = (const float*)d_in[0];
  const float* centers = (const float*)d_in[1];
  const float* gamma   = (const float*)d_in[2];
  const float* norm    = (const float*)d_in[3];
  float* out = (float*)d_out;

  char* ws = (char*)d_ws;
  short* inb  = (short*)(ws);                            // 16 MiB  bf16 inputs
  short* cenb = (short*)(ws + (16u << 20));              //  1 MiB  bf16 centers
  short* wT   = (short*)(ws + (17u << 20));              //  2 MiB  bf16 norm^T
  float* x2   = (float*)(ws + (19u << 20));              // 64 KiB  ||x||^2
  float* c2   = (float*)(ws + (19u << 20) + (1u << 16)); //  4 KiB  ||c||^2
  short* dens = (short*)(ws + (20u << 20));              // 32 MiB  bf16 densities

  fused_prep<<<5376, 256, 0, stream>>>(inputs, centers, norm, inb, cenb, wT, x2, c2);
  gemm256<0><<<256, 512, 0, stream>>>(inb, cenb, dens, x2, c2, gamma, D_DIM);
  gemm256<1><<<256, 512, 0, stream>>>(dens, wT, out, nullptr, nullptr, nullptr, C_DIM);
}